// Round 8
// baseline (298.319 us; speedup 1.0000x reference)
//
#include <hip/hip_runtime.h>
#include <hip/hip_bf16.h>

#define BB 32
#define NN 1025
#define CC 512
#define HH 8
#define HD 64
#define MM (BB * NN)        // 32800
#define MP 33024            // padded plane rows (129 * 256)
#define KK 512
#define SCALE 0.125f

typedef unsigned short u16;
typedef __attribute__((ext_vector_type(4))) unsigned short u16x4;
typedef __attribute__((ext_vector_type(8))) unsigned short u16x8;
typedef __attribute__((ext_vector_type(4))) float f32x4;
typedef __attribute__((ext_vector_type(8))) __bf16 bf16x8;

__device__ __forceinline__ u16 f2bf(float f) {
    unsigned u = __float_as_uint(f);
    unsigned r = (u + 0x7FFFu + ((u >> 16) & 1u)) >> 16;
    return (u16)r;
}
__device__ __forceinline__ float bf2f(u16 h) {
    return __uint_as_float((unsigned)h << 16);
}

__device__ __forceinline__ void gload16(const u16* g, u16* l) {
    __builtin_amdgcn_global_load_lds(
        (const __attribute__((address_space(1))) unsigned int*)g,
        (__attribute__((address_space(3))) unsigned int*)l, 16, 0, 0);
}

// ---------------------------------------------------------------------------
// convert x (fp32 [MM][512]) -> xbf (bf16 [MP][512]), zero pad rows
// ---------------------------------------------------------------------------
__global__ __launch_bounds__(256) void convert_x_kernel(
    const float* __restrict__ x, u16* __restrict__ xbf)
{
    size_t t = (size_t)blockIdx.x * 256 + threadIdx.x;
    size_t base = t * 8;
    u16x8 o;
    if (base < (size_t)MM * CC) {
        f32x4 a = *(const f32x4*)&x[base];
        f32x4 b = *(const f32x4*)&x[base + 4];
#pragma unroll
        for (int j = 0; j < 4; j++) { o[j] = f2bf(a[j]); o[j + 4] = f2bf(b[j]); }
    } else {
#pragma unroll
        for (int j = 0; j < 8; j++) o[j] = 0;
    }
    *(u16x8*)&xbf[base] = o;
}

// ---------------------------------------------------------------------------
// transpose+convert weights: Wt[n][k] = bf16(W[k][n]);  K = 512
// ---------------------------------------------------------------------------
__global__ __launch_bounds__(256) void convert_wt_kernel(
    const float* __restrict__ W, u16* __restrict__ Wt, int N)
{
    int t = blockIdx.x * 256 + threadIdx.x;
    int n = t >> 6;
    int k0 = (t & 63) * 8;
    u16x8 o;
#pragma unroll
    for (int j = 0; j < 8; j++) o[j] = f2bf(W[(size_t)(k0 + j) * N + n]);
    *(u16x8*)&Wt[(size_t)n * KK + k0] = o;
}

// ---------------------------------------------------------------------------
// expand conv weights into dense [7][7][512] table (+ merged bias [512])
// ---------------------------------------------------------------------------
__global__ __launch_bounds__(256) void prep_w7_kernel(
    const float* __restrict__ ck3, const float* __restrict__ cb3,
    const float* __restrict__ ck5, const float* __restrict__ cb5,
    const float* __restrict__ ck7, const float* __restrict__ cb7,
    float* __restrict__ w7, float* __restrict__ cbx)
{
    int t = blockIdx.x * 256 + threadIdx.x;   // 49*512 = 25088
    if (t >= 49 * 512) return;
    int c = t & 511;
    int tap = t >> 9;
    int dy = tap / 7, dx = tap % 7;
    float w = 0.f;
    if (c < 128) {
        int ry = dy - 2, rx = dx - 2;
        if (ry >= 0 && ry < 3 && rx >= 0 && rx < 3) w = ck3[(ry * 3 + rx) * 128 + c];
    } else if (c < 320) {
        int ry = dy - 1, rx = dx - 1;
        if (ry >= 0 && ry < 5 && rx >= 0 && rx < 5) w = ck5[(ry * 5 + rx) * 192 + (c - 128)];
    } else {
        w = ck7[(dy * 7 + dx) * 192 + (c - 320)];
    }
    w7[tap * 512 + c] = w;
    if (t < 512)
        cbx[t] = (t < 128) ? cb3[t] : (t < 320) ? cb5[t - 128] : cb7[t - 320];
}

// ---------------------------------------------------------------------------
// 8-phase 256x256 bf16 MFMA GEMM (qkv only). 512 thr = 8 waves (2M x 4N).
// BK=64, 2 LDS buffers; per K-tile 4 phases = C-quadrants (qr,qc):
//   ph1 (h0,h0): read A-h0+B-h0, stage A-h1(t+1)
//   ph2 (h0,h1): read B-h1 (A cached), stage B-h1(t+1)
//   ph3 (h1,h0): read A-h1+B-h0, stage A-h0(t+2)
//   ph4 (h1,h1): read B-h1 (A cached), stage B-h0(t+2), vmcnt(4)
// Raw s_barrier (no vmcnt drain); per-wave vmcnt(4) + barrier proves tile
// t+1 fully in LDS before its first read. Scatters bf16 to q/k/v planes.
// ---------------------------------------------------------------------------
__device__ __forceinline__ void vmwait(int n) {
    if (n == 4)      asm volatile("s_waitcnt vmcnt(4)" ::: "memory");
    else if (n == 0) asm volatile("s_waitcnt vmcnt(0)" ::: "memory");
}

template <int GX>
__global__ __launch_bounds__(512, 2) void gemm8p_qkv_kernel(
    const u16* __restrict__ A, const u16* __restrict__ Bt,
    const float* __restrict__ bias, u16* __restrict__ qkv, int nwg)
{
    __shared__ __align__(16) u16 lds[65536];  // [buf2][AB2][half2][128][64]

    int wg = blockIdx.x;
    {
        int q = nwg >> 3, r = nwg & 7;
        int xcd = wg & 7, pos = wg >> 3;
        wg = (xcd < r ? xcd * (q + 1) : r * (q + 1) + (xcd - r) * q) + pos;
    }
    const int m0 = (wg / GX) * 256;
    const int n0 = (wg % GX) * 256;

    const int t = threadIdx.x;
    const int l = t & 63;
    const int w = t >> 6;
    const int wr = w >> 2;          // 0..1 (M)
    const int wc = w & 3;           // 0..3 (N)
    const int lr = l & 15;
    const int lk = l >> 4;          // 0..3

    // staging: thread -> local row t>>3 (0..63), 16B slot t&7; source
    // pre-swizzled so LDS[r][s] holds global k-slot s^(r&7)  (rule #21)
    const int srow = t >> 3;
    const int sslot = t & 7;
    const u16* gA = A  + (size_t)(m0 + srow) * KK + (sslot ^ (srow & 7)) * 8;
    const u16* gB = Bt + (size_t)(n0 + srow) * KK + (sslot ^ (srow & 7)) * 8;

#define STG8(TT, AB, H) do {                                                  \
        const u16* g_ = ((AB) ? gB : gA) + (size_t)(H) * 128 * KK + (TT) * 64;\
        u16* d_ = lds + ((TT) & 1) * 32768 + (AB) * 16384 + (H) * 8192 + t * 8;\
        gload16(g_, d_);                                                      \
        gload16(g_ + (size_t)64 * KK, d_ + 4096);                             \
    } while (0)

    // read offsets (u16 units); swizzled slot = (kh*4+lk) ^ (lr&7)
    int aoff[4][2], boff[2][2];
#pragma unroll
    for (int fi = 0; fi < 4; fi++)
#pragma unroll
        for (int kh = 0; kh < 2; kh++)
            aoff[fi][kh] = (wr * 64 + fi * 16 + lr) * 64
                         + (((kh * 4 + lk) ^ (lr & 7)) * 8);
#pragma unroll
    for (int fj = 0; fj < 2; fj++)
#pragma unroll
        for (int kh = 0; kh < 2; kh++)
            boff[fj][kh] = 16384 + (wc * 32 + fj * 16 + lr) * 64
                         + (((kh * 4 + lk) ^ (lr & 7)) * 8);

    f32x4 acc[2][2][4][2] = {};
    bf16x8 a_[4][2], b_[2][2];

#define PHASE8(QR, QC, READA, COND, STGX, VMN) do {                           \
        u16* cur_ = lds + (tt & 1) * 32768;                                   \
        if (READA) {                                                          \
            _Pragma("unroll") for (int fi = 0; fi < 4; fi++)                  \
            _Pragma("unroll") for (int kh = 0; kh < 2; kh++)                  \
                a_[fi][kh] = *(const bf16x8*)&cur_[(QR) * 8192 + aoff[fi][kh]];\
        }                                                                     \
        _Pragma("unroll") for (int fj = 0; fj < 2; fj++)                      \
        _Pragma("unroll") for (int kh = 0; kh < 2; kh++)                      \
            b_[fj][kh] = *(const bf16x8*)&cur_[(QC) * 8192 + boff[fj][kh]];   \
        if (COND) { STGX; }                                                   \
        asm volatile("s_barrier" ::: "memory");                               \
        __builtin_amdgcn_s_setprio(1);                                        \
        _Pragma("unroll") for (int fi = 0; fi < 4; fi++)                      \
        _Pragma("unroll") for (int fj = 0; fj < 2; fj++)                      \
        _Pragma("unroll") for (int kh = 0; kh < 2; kh++)                      \
            acc[QR][QC][fi][fj] = __builtin_amdgcn_mfma_f32_16x16x32_bf16(    \
                a_[fi][kh], b_[fj][kh], acc[QR][QC][fi][fj], 0, 0, 0);        \
        __builtin_amdgcn_s_setprio(0);                                        \
        vmwait(VMN);                                                          \
        asm volatile("s_barrier" ::: "memory");                               \
    } while (0)

    // prologue: tile0 fully + tile1 h0 halves (12 gloads); wait tile0 (8)
    STG8(0, 0, 0); STG8(0, 1, 0); STG8(0, 0, 1); STG8(0, 1, 1);
    STG8(1, 0, 0); STG8(1, 1, 0);
    asm volatile("s_waitcnt vmcnt(4)" ::: "memory");
    asm volatile("s_barrier" ::: "memory");

    for (int tt = 0; tt < 8; ++tt) {
        PHASE8(0, 0, true,  tt < 7, STG8(tt + 1, 0, 1), -1);
        PHASE8(0, 1, false, tt < 7, STG8(tt + 1, 1, 1), -1);
        PHASE8(1, 0, true,  tt < 6, STG8(tt + 2, 0, 0), -1);
        PHASE8(1, 1, false, tt < 6, STG8(tt + 2, 1, 0),
               (tt < 6) ? 4 : ((tt == 6) ? 0 : -1));
    }
#undef PHASE8
#undef STG8

    // epilogue: C row = m0+qr*128+wr*64+fi*16+lk*4+rr, col = n0+qc*128+wc*32+fj*16+lr
    const int plane = n0 >> 9;
    u16* pl = qkv + (size_t)plane * ((size_t)MP * CC);
    const int cbase = (n0 & 511) + wc * 32 + lr;
#pragma unroll
    for (int qc = 0; qc < 2; qc++) {
#pragma unroll
        for (int fj = 0; fj < 2; fj++) {
            float bs = bias[n0 + qc * 128 + wc * 32 + fj * 16 + lr];
#pragma unroll
            for (int qr = 0; qr < 2; qr++) {
#pragma unroll
                for (int fi = 0; fi < 4; fi++) {
#pragma unroll
                    for (int rr = 0; rr < 4; rr++) {
                        int gm = m0 + qr * 128 + wr * 64 + fi * 16 + lk * 4 + rr;
                        pl[(size_t)gm * CC + cbase + qc * 128 + fj * 16] =
                            f2bf(acc[qr][qc][fi][fj][rr] + bs);
                    }
                }
            }
        }
    }
}

// ---------------------------------------------------------------------------
// bf16 MFMA GEMM (2-phase 128x128, BK=32) + XCD swizzle — proj only (fp32 out)
// ---------------------------------------------------------------------------
template <int NSZ, int GX>
__global__ __launch_bounds__(256) void gemm_bf16_kernel(
    const u16* __restrict__ A, const u16* __restrict__ Bt,
    const float* __restrict__ bias, float* __restrict__ out, int nwg)
{
    __shared__ __align__(16) u16 lds[2][2][4096];

    int wg = blockIdx.x;
    {
        int q = nwg >> 3, r = nwg & 7;
        int xcd = wg & 7, pos = wg >> 3;
        wg = (xcd < r ? xcd * (q + 1) : r * (q + 1) + (xcd - r) * q) + pos;
    }
    const int m0 = (wg / GX) * 128;
    const int n0 = (wg % GX) * 128;

    const int t = threadIdx.x;

    const int srow = t >> 2;
    const int ps   = t & 3;
    const int ls   = ps ^ ((srow >> 1) & 3);
    const u16* gA = A  + (size_t)(m0 + srow) * KK + ls * 8;
    const u16* gB = Bt + (size_t)(n0 + srow) * KK + ls * 8;

    const int l  = t & 63;
    const int w  = t >> 6;
    const int wm = (w >> 1) * 64;
    const int wn = (w & 1) * 64;
    const int lr = l & 15;
    const int s  = l >> 4;
    const int ra = wm + lr;
    const int rb = wn + lr;
    const int offA = ra * 32 + (s ^ ((ra >> 1) & 3)) * 8;
    const int offB = rb * 32 + (s ^ ((rb >> 1) & 3)) * 8;

    f32x4 acc[4][4] = {};

#define STAGE(buf, kk_) do {                                        \
        gload16(gA + (kk_),           &lds[buf][0][t * 8]);         \
        gload16(gA + 64 * KK + (kk_), &lds[buf][0][2048 + t * 8]);  \
        gload16(gB + (kk_),           &lds[buf][1][t * 8]);         \
        gload16(gB + 64 * KK + (kk_), &lds[buf][1][2048 + t * 8]);  \
    } while (0)

    STAGE(0, 0);
    __syncthreads();

    int cur = 0;
    for (int step = 0; step < 16; ++step) {
        if (step < 15) STAGE(cur ^ 1, (step + 1) * 32);
        bf16x8 a[4], b[4];
#pragma unroll
        for (int i = 0; i < 4; i++) a[i] = *(const bf16x8*)&lds[cur][0][offA + i * 512];
#pragma unroll
        for (int i = 0; i < 4; i++) b[i] = *(const bf16x8*)&lds[cur][1][offB + i * 512];
#pragma unroll
        for (int i = 0; i < 4; i++)
#pragma unroll
            for (int j = 0; j < 4; j++)
                acc[i][j] = __builtin_amdgcn_mfma_f32_16x16x32_bf16(a[i], b[j], acc[i][j], 0, 0, 0);
        __syncthreads();
        cur ^= 1;
    }
#undef STAGE

    const int row0 = m0 + wm + (l >> 4) * 4;
    const int col0 = n0 + wn + lr;
    float bs[4];
#pragma unroll
    for (int j = 0; j < 4; j++) bs[j] = bias[col0 + j * 16];

#pragma unroll
    for (int i = 0; i < 4; i++) {
#pragma unroll
        for (int j = 0; j < 4; j++) {
            int gn = col0 + j * 16;
#pragma unroll
            for (int r = 0; r < 4; r++) {
                int gm = row0 + i * 16 + r;
                if (gm < MM) out[(size_t)gm * NSZ + gn] = acc[i][j][r] + bs[j];
            }
        }
    }
}

// ---------------------------------------------------------------------------
// softmax stats over N per (b,c): 8 N-chunks, then merge
// ---------------------------------------------------------------------------
__global__ __launch_bounds__(256) void stats_part_kernel(
    const u16* __restrict__ kbf, float* __restrict__ pmax, float* __restrict__ psum)
{
    int c  = blockIdx.x * 256 + threadIdx.x;
    int b  = blockIdx.y;
    int ch = blockIdx.z;
    int n0 = ch * 128, n1 = (ch == 7) ? NN : n0 + 128;
    const u16* col = kbf + (size_t)(b * NN + n0) * CC + c;
    float m = -1e30f, sum = 0.f;
    for (int n = n0; n < n1; n++, col += CC) {
        float val = bf2f(*col);
        float nm = fmaxf(m, val);
        sum = sum * __expf(m - nm) + __expf(val - nm);
        m = nm;
    }
    pmax[(ch * BB + b) * CC + c] = m;
    psum[(ch * BB + b) * CC + c] = sum;
}

__global__ __launch_bounds__(256) void stats_merge_kernel(
    const float* __restrict__ pmax, const float* __restrict__ psum,
    float* __restrict__ colmax, float* __restrict__ colsum)
{
    int i = blockIdx.x * 256 + threadIdx.x;
    float m = -1e30f, sum = 0.f;
#pragma unroll
    for (int ch = 0; ch < 8; ch++) {
        float mm = pmax[ch * (BB * CC) + i];
        float ss = psum[ch * (BB * CC) + i];
        float nm = fmaxf(m, mm);
        sum = sum * __expf(m - nm) + ss * __expf(mm - nm);
        m = nm;
    }
    colmax[i] = m;
    colsum[i] = sum;
}

// ---------------------------------------------------------------------------
// ksv partials: part[chunk][bh][kk][vv] = sum_{n in chunk} exp(k-max) * v
// ---------------------------------------------------------------------------
__global__ __launch_bounds__(256) void ksv_part_kernel(
    const u16* __restrict__ kbf, const u16* __restrict__ vbf,
    const float* __restrict__ colmax, float* __restrict__ part)
{
    int bh = blockIdx.x;
    int chunk = blockIdx.y;
    int b = bh >> 3, h = bh & 7;
    int n0 = chunk * 256;
    int n1 = (chunk == 3) ? NN : n0 + 256;

    __shared__ float ke[16][64];
    __shared__ float ve[16][64];
    __shared__ float cm[64];

    int t = threadIdx.x;
    int lrow = t >> 4;
    int lcol = (t & 15) * 4;
    int tx = t & 15, ty = t >> 4;
    if (t < 64) cm[t] = colmax[b * CC + h * HD + t];
    __syncthreads();

    float acc[4][4] = {};
    for (int nb = n0; nb < n1; nb += 16) {
        int n = nb + lrow;
        bool valid = n < n1;
        size_t off = ((size_t)(b * NN + n)) * CC + h * HD + lcol;  // padded plane
        u16x4 kr = *(const u16x4*)&kbf[off];
        u16x4 vr = *(const u16x4*)&vbf[off];
#pragma unroll
        for (int j = 0; j < 4; j++) {
            ke[lrow][lcol + j] = valid ? __expf(bf2f(kr[j]) - cm[lcol + j]) : 0.f;
            ve[lrow][lcol + j] = valid ? bf2f(vr[j]) : 0.f;
        }
        __syncthreads();
#pragma unroll 4
        for (int d = 0; d < 16; d++) {
            f32x4 ka = *(const f32x4*)&ke[d][ty * 4];
            f32x4 vb = *(const f32x4*)&ve[d][tx * 4];
#pragma unroll
            for (int i = 0; i < 4; i++)
#pragma unroll
                for (int j = 0; j < 4; j++)
                    acc[i][j] = fmaf(ka[i], vb[j], acc[i][j]);
        }
        __syncthreads();
    }

    float* dst = part + ((size_t)chunk * 256 + bh) * 4096;
#pragma unroll
    for (int i = 0; i < 4; i++) {
        f32x4 o = {acc[i][0], acc[i][1], acc[i][2], acc[i][3]};
        *(f32x4*)&dst[(ty * 4 + i) * 64 + tx * 4] = o;
    }
}

// ---------------------------------------------------------------------------
// ksvT[bh][vv][kk] = bf16( SCALE * (sum_chunk part[bh][kk][vv]) / colsum[kk] )
// ---------------------------------------------------------------------------
__global__ __launch_bounds__(256) void ksv_reduceT_kernel(
    const float* __restrict__ part, const float* __restrict__ colsum,
    u16* __restrict__ ksvT)
{
    int i = blockIdx.x * 256 + threadIdx.x;   // f32x4 units
    size_t e = (size_t)i * 4;
    int bh = (int)(e >> 12);
    int kk = ((int)e >> 6) & 63;
    int vv0 = (int)e & 63;
    int b = bh >> 3, h = bh & 7;
    f32x4 s = *(const f32x4*)&part[e];
#pragma unroll
    for (int c = 1; c < 4; c++) {
        f32x4 p = *(const f32x4*)&part[(size_t)c * 256 * 4096 + e];
#pragma unroll
        for (int j = 0; j < 4; j++) s[j] += p[j];
    }
    float inv = SCALE / colsum[b * CC + h * HD + kk];
#pragma unroll
    for (int j = 0; j < 4; j++)
        ksvT[(size_t)bh * 4096 + (vv0 + j) * 64 + kk] = f2bf(s[j] * inv);
}

// ---------------------------------------------------------------------------
// factor att via MFMA: attbf[b,n,h,:] = bf16( q[b,n,h,:] @ ksvT[b,h]^T )
// ---------------------------------------------------------------------------
__global__ __launch_bounds__(256) void factor_mfma_kernel(
    const u16* __restrict__ qbf, const u16* __restrict__ ksvT,
    u16* __restrict__ attbf)
{
    int bh = blockIdx.y;
    int b = bh >> 3, h = bh & 7;
    int n0 = blockIdx.x * 128;

    __shared__ __align__(16) u16 lq[128 * 64];
    __shared__ __align__(16) u16 lk[64 * 64];

    int t = threadIdx.x;
#pragma unroll
    for (int i = 0; i < 4; i++) {
        int idx = t + i * 256;
        int row = idx >> 3, sl = idx & 7;
        u16x8 v = *(const u16x8*)&qbf[((size_t)(b * NN + n0 + row)) * CC + h * HD + sl * 8];
        *(u16x8*)&lq[row * 64 + ((sl ^ (row & 7)) * 8)] = v;
    }
#pragma unroll
    for (int i = 0; i < 2; i++) {
        int idx = t + i * 256;
        int col = idx >> 3, sl = idx & 7;
        u16x8 v = *(const u16x8*)&ksvT[(size_t)bh * 4096 + col * 64 + sl * 8];
        *(u16x8*)&lk[col * 64 + ((sl ^ (col & 7)) * 8)] = v;
    }
    __syncthreads();

    int l = t & 63, w = t >> 6;
    int lr = l & 15, ls = l >> 4;
    f32x4 acc[2][4] = {};
#pragma unroll
    for (int kf = 0; kf < 2; kf++) {
        bf16x8 a[2], bf[4];
#pragma unroll
        for (int i = 0; i < 2; i++) {
            int row = w * 32 + i * 16 + lr;
            int sl = kf * 4 + ls;
            a[i] = *(const bf16x8*)&lq[row * 64 + ((sl ^ (row & 7)) * 8)];
        }
#pragma unroll
        for (int j = 0; j < 4; j++) {
            int col = j * 16 + lr;
            int sl = kf * 4 + ls;
            bf[j] = *(const bf16x8*)&lk[col * 64 + ((sl ^ (col & 7)) * 8)];
        }
#pragma unroll
        for (int i = 0; i < 2; i++)
#pragma unroll
            for (int j = 0; j < 4; j++)
                acc[i][j] = __builtin_amdgcn_mfma_f32_16x16x32_bf16(a[i], bf[j], acc[i][j], 0, 0, 0);
    }

#pragma unroll
    for (int i = 0; i < 2; i++) {
#pragma unroll
        for (int r = 0; r < 4; r++) {
            int n = n0 + w * 32 + i * 16 + ls * 4 + r;
            if (n >= NN) continue;
            u16* dst = attbf + ((size_t)(b * NN + n)) * CC + h * HD;
#pragma unroll
            for (int j = 0; j < 4; j++)
                dst[j * 16 + lr] = f2bf(acc[i][j][r]);
        }
    }
}

// ---------------------------------------------------------------------------
// CRPE RMW: branchless clamped tap loads, batched per dy-row. 8px x 4ch.
// ---------------------------------------------------------------------------
__global__ __launch_bounds__(256) void conv_rmw_kernel(
    const u16* __restrict__ vbf, const u16* __restrict__ qbf,
    const float* __restrict__ w7, const float* __restrict__ cbx,
    u16* __restrict__ attbf)
{
    int blk = blockIdx.x;           // (b*32 + y)*2 + chalf
    int chalf = blk & 1;
    int by = blk >> 1;
    int b = by >> 5, y = by & 31;
    int t = threadIdx.x;
    int xo = t >> 6;                // wave-uniform x-octet
    int c = (chalf * 64 + (t & 63)) * 4;
    const int x0 = xo * 8;

    const u16* vimg = vbf + ((size_t)(b * NN) + 1) * CC + c;

    float acc[8][4];
    {
        f32x4 b0 = *(const f32x4*)&cbx[c];
#pragma unroll
        for (int xi = 0; xi < 8; xi++)
#pragma unroll
            for (int j = 0; j < 4; j++) acc[xi][j] = b0[j];
    }

    for (int dy = 0; dy < 7; dy++) {
        int yy = y + dy - 3;
        if (yy < 0 || yy >= 32) continue;            // block-uniform skip
        float wr[7][4];
#pragma unroll
        for (int dx = 0; dx < 7; dx++)
            *(f32x4*)&wr[dx][0] = *(const f32x4*)&w7[(dy * 7 + dx) * 512 + c];
        const u16* vrow = vimg + (size_t)yy * 32 * CC;
        u16x4 vv[14];
#pragma unroll
        for (int sxi = 0; sxi < 14; sxi++) {
            int sx = x0 - 3 + sxi;
            int sxc = sx < 0 ? 0 : (sx > 31 ? 31 : sx);
            vv[sxi] = *(const u16x4*)&vrow[(size_t)sxc * CC];
        }
#pragma unroll
        for (int sxi = 0; sxi < 14; sxi++) {
            int sx = x0 - 3 + sxi;
            bool xval = (sx >= 0) && (sx < 32);
            float vf[4];
#pragma unroll
            for (int j = 0; j < 4; j++) vf[j] = xval ? bf2f(vv[sxi][j]) : 0.f;
            int lo = sxi - 6 > 0 ? sxi - 6 : 0;
            int hi = sxi < 7 ? sxi : 7;
#pragma unroll
            for (int xi = 0; xi < 8; xi++) {
                if (xi < lo || xi > hi) continue;
                int dx = sxi - xi;
#pragma unroll
                for (int j = 0; j < 4; j++)
                    acc[xi][j] = fmaf(vf[j], wr[dx][j], acc[xi][j]);
            }
        }
    }

    const size_t rowbase = (size_t)(b * NN) + 1 + (size_t)y * 32 + x0;
    u16x4 qv[8], av[8];
#pragma unroll
    for (int xi = 0; xi < 8; xi++) {
        size_t o = (rowbase + xi) * CC + c;
        qv[xi] = *(const u16x4*)&qbf[o];
        av[xi] = *(const u16x4*)&attbf[o];
    }
#pragma unroll
    for (int xi = 0; xi < 8; xi++) {
        size_t o = (rowbase + xi) * CC + c;
        u16x4 ov;
#pragma unroll
        for (int j = 0; j < 4; j++)
            ov[j] = f2bf(bf2f(av[xi][j]) + bf2f(qv[xi][j]) * acc[xi][j]);
        *(u16x4*)&attbf[o] = ov;
    }
}

// ---------------------------------------------------------------------------
extern "C" void kernel_launch(void* const* d_in, const int* in_sizes, int n_in,
                              void* d_out, int out_size, void* d_ws, size_t ws_size,
                              hipStream_t stream)
{
    const float* x     = (const float*)d_in[0];
    const float* Wqkv  = (const float*)d_in[1];
    const float* bqkv  = (const float*)d_in[2];
    const float* Wproj = (const float*)d_in[3];
    const float* bproj = (const float*)d_in[4];
    const float* ck3   = (const float*)d_in[5];
    const float* cb3   = (const float*)d_in[6];
    const float* ck5   = (const float*)d_in[7];
    const float* cb5   = (const float*)d_in[8];
    const float* ck7   = (const float*)d_in[9];
    const float* cb7   = (const float*)d_in[10];
    float* out = (float*)d_out;

    const size_t PLANE = (size_t)MP * CC;

    u16* xbf  = (u16*)d_ws;
    u16* qbf  = xbf + PLANE;
    u16* kbf  = qbf + PLANE;
    u16* vbf  = kbf + PLANE;
    u16* wqT  = vbf + PLANE;
    u16* wpT  = wqT + (size_t)1536 * 512;
    u16* ksvT = wpT + (size_t)512 * 512;           // 256*4096 bf16
    float* pmax   = (float*)(ksvT + (size_t)256 * 4096);
    float* psum   = pmax + 8 * BB * CC;
    float* colmax = psum + 8 * BB * CC;
    float* colsum = colmax + BB * CC;
    float* part   = colsum + BB * CC;              // 4 * 256 * 4096 f32
    float* w7     = part + (size_t)4 * 256 * 4096; // 49*512
    float* cbx    = w7 + 49 * 512;                 // 512
    u16* attbf = xbf;                              // alias (x dead after qkv)

    // 1) converts + conv-weight expansion
    convert_x_kernel<<<(int)(PLANE / 8 / 256), 256, 0, stream>>>(x, xbf);
    convert_wt_kernel<<<1536 * 64 / 256, 256, 0, stream>>>(Wqkv, wqT, 1536);
    convert_wt_kernel<<<512 * 64 / 256, 256, 0, stream>>>(Wproj, wpT, 512);
    prep_w7_kernel<<<98, 256, 0, stream>>>(ck3, cb3, ck5, cb5, ck7, cb7, w7, cbx);

    // 2) qkv GEMM (8-phase 256^2) -> bf16 q/k/v planes
    {
        int nwg = 6 * (MP / 256);    // 774
        gemm8p_qkv_kernel<6><<<nwg, 512, 0, stream>>>(xbf, wqT, bqkv, qbf, nwg);
    }
    // 3) softmax stats
    {
        dim3 grid(CC / 256, BB, 8);
        stats_part_kernel<<<grid, 256, 0, stream>>>(kbf, pmax, psum);
        stats_merge_kernel<<<BB * CC / 256, 256, 0, stream>>>(pmax, psum, colmax, colsum);
    }
    // 4) ksv partials + transpose-reduce (folds SCALE/colsum, emits bf16 B^T)
    {
        dim3 grid(BB * HH, 4);
        ksv_part_kernel<<<grid, 256, 0, stream>>>(kbf, vbf, colmax, part);
        ksv_reduceT_kernel<<<256 * 4096 / 4 / 256, 256, 0, stream>>>(part, colsum, ksvT);
    }
    // 5) factor att via MFMA -> attbf (all n, incl n=0)
    {
        dim3 grid((NN + 127) / 128, BB * HH);      // 9 x 256
        factor_mfma_kernel<<<grid, 256, 0, stream>>>(qbf, ksvT, attbf);
    }
    // 6) CRPE RMW (branchless batched loads)
    conv_rmw_kernel<<<BB * 32 * 2, 256, 0, stream>>>(vbf, qbf, w7, cbx, attbf);
    // 7) proj GEMM -> out
    {
        int nwg = 4 * (MP / 128);    // 1032
        gemm_bf16_kernel<512, 4><<<nwg, 256, 0, stream>>>(attbf, wpT, bproj, out, nwg);
    }
}

// Round 9
// 237.580 us; speedup vs baseline: 1.2557x; 1.2557x over previous
//
#include <hip/hip_runtime.h>
#include <hip/hip_bf16.h>

#define BB 32
#define NN 1025
#define CC 512
#define HH 8
#define HD 64
#define MM (BB * NN)        // 32800
#define MP 33024            // padded plane rows (258 * 128)
#define KK 512
#define SCALE 0.125f

typedef unsigned short u16;
typedef __attribute__((ext_vector_type(4))) unsigned short u16x4;
typedef __attribute__((ext_vector_type(8))) unsigned short u16x8;
typedef __attribute__((ext_vector_type(4))) float f32x4;
typedef __attribute__((ext_vector_type(8))) __bf16 bf16x8;

__device__ __forceinline__ u16 f2bf(float f) {
    unsigned u = __float_as_uint(f);
    unsigned r = (u + 0x7FFFu + ((u >> 16) & 1u)) >> 16;
    return (u16)r;
}
__device__ __forceinline__ float bf2f(u16 h) {
    return __uint_as_float((unsigned)h << 16);
}

__device__ __forceinline__ void gload16(const u16* g, u16* l) {
    __builtin_amdgcn_global_load_lds(
        (const __attribute__((address_space(1))) unsigned int*)g,
        (__attribute__((address_space(3))) unsigned int*)l, 16, 0, 0);
}

// ---------------------------------------------------------------------------
// convert x (fp32 [MM][512]) -> xbf (bf16 [MP][512]), zero pad rows
// ---------------------------------------------------------------------------
__global__ __launch_bounds__(256) void convert_x_kernel(
    const float* __restrict__ x, u16* __restrict__ xbf)
{
    size_t t = (size_t)blockIdx.x * 256 + threadIdx.x;
    size_t base = t * 8;
    u16x8 o;
    if (base < (size_t)MM * CC) {
        f32x4 a = *(const f32x4*)&x[base];
        f32x4 b = *(const f32x4*)&x[base + 4];
#pragma unroll
        for (int j = 0; j < 4; j++) { o[j] = f2bf(a[j]); o[j + 4] = f2bf(b[j]); }
    } else {
#pragma unroll
        for (int j = 0; j < 8; j++) o[j] = 0;
    }
    *(u16x8*)&xbf[base] = o;
}

// ---------------------------------------------------------------------------
// transpose+convert weights: Wt[n][k] = bf16(W[k][n]);  K = 512
// ---------------------------------------------------------------------------
__global__ __launch_bounds__(256) void convert_wt_kernel(
    const float* __restrict__ W, u16* __restrict__ Wt, int N)
{
    int t = blockIdx.x * 256 + threadIdx.x;
    int n = t >> 6;
    int k0 = (t & 63) * 8;
    u16x8 o;
#pragma unroll
    for (int j = 0; j < 8; j++) o[j] = f2bf(W[(size_t)(k0 + j) * N + n]);
    *(u16x8*)&Wt[(size_t)n * KK + k0] = o;
}

// ---------------------------------------------------------------------------
// expand conv weights into dense [7][7][512] table (+ merged bias [512])
// ---------------------------------------------------------------------------
__global__ __launch_bounds__(256) void prep_w7_kernel(
    const float* __restrict__ ck3, const float* __restrict__ cb3,
    const float* __restrict__ ck5, const float* __restrict__ cb5,
    const float* __restrict__ ck7, const float* __restrict__ cb7,
    float* __restrict__ w7, float* __restrict__ cbx)
{
    int t = blockIdx.x * 256 + threadIdx.x;   // 49*512 = 25088
    if (t >= 49 * 512) return;
    int c = t & 511;
    int tap = t >> 9;
    int dy = tap / 7, dx = tap % 7;
    float w = 0.f;
    if (c < 128) {
        int ry = dy - 2, rx = dx - 2;
        if (ry >= 0 && ry < 3 && rx >= 0 && rx < 3) w = ck3[(ry * 3 + rx) * 128 + c];
    } else if (c < 320) {
        int ry = dy - 1, rx = dx - 1;
        if (ry >= 0 && ry < 5 && rx >= 0 && rx < 5) w = ck5[(ry * 5 + rx) * 192 + (c - 128)];
    } else {
        w = ck7[(dy * 7 + dx) * 192 + (c - 320)];
    }
    w7[tap * 512 + c] = w;
    if (t < 512)
        cbx[t] = (t < 128) ? cb3[t] : (t < 320) ? cb5[t - 128] : cb7[t - 320];
}

// ---------------------------------------------------------------------------
// bf16 MFMA GEMM (2-phase 128x128, BK=32) + XCD-bijective 1D swizzle.
// MODE 0: scatter bf16 into contiguous q/k/v planes. MODE 1: fp32 out.
// ---------------------------------------------------------------------------
template <int MODE, int NSZ, int GX>
__global__ __launch_bounds__(256) void gemm_bf16_kernel(
    const u16* __restrict__ A, const u16* __restrict__ Bt,
    const float* __restrict__ bias, void* __restrict__ outv, int nwg)
{
    __shared__ __align__(16) u16 lds[2][2][4096];

    int wg = blockIdx.x;
    {
        int q = nwg >> 3, r = nwg & 7;
        int xcd = wg & 7, pos = wg >> 3;
        wg = (xcd < r ? xcd * (q + 1) : r * (q + 1) + (xcd - r) * q) + pos;
    }
    const int m0 = (wg / GX) * 128;
    const int n0 = (wg % GX) * 128;

    const int t = threadIdx.x;

    const int srow = t >> 2;
    const int ps   = t & 3;
    const int ls   = ps ^ ((srow >> 1) & 3);
    const u16* gA = A  + (size_t)(m0 + srow) * KK + ls * 8;
    const u16* gB = Bt + (size_t)(n0 + srow) * KK + ls * 8;

    const int l  = t & 63;
    const int w  = t >> 6;
    const int wm = (w >> 1) * 64;
    const int wn = (w & 1) * 64;
    const int lr = l & 15;
    const int s  = l >> 4;
    const int ra = wm + lr;
    const int rb = wn + lr;
    const int offA = ra * 32 + (s ^ ((ra >> 1) & 3)) * 8;
    const int offB = rb * 32 + (s ^ ((rb >> 1) & 3)) * 8;

    f32x4 acc[4][4] = {};

#define STAGE(buf, kk_) do {                                        \
        gload16(gA + (kk_),           &lds[buf][0][t * 8]);         \
        gload16(gA + 64 * KK + (kk_), &lds[buf][0][2048 + t * 8]);  \
        gload16(gB + (kk_),           &lds[buf][1][t * 8]);         \
        gload16(gB + 64 * KK + (kk_), &lds[buf][1][2048 + t * 8]);  \
    } while (0)

    STAGE(0, 0);
    __syncthreads();

    int cur = 0;
    for (int step = 0; step < 16; ++step) {
        if (step < 15) STAGE(cur ^ 1, (step + 1) * 32);
        bf16x8 a[4], b[4];
#pragma unroll
        for (int i = 0; i < 4; i++) a[i] = *(const bf16x8*)&lds[cur][0][offA + i * 512];
#pragma unroll
        for (int i = 0; i < 4; i++) b[i] = *(const bf16x8*)&lds[cur][1][offB + i * 512];
#pragma unroll
        for (int i = 0; i < 4; i++)
#pragma unroll
            for (int j = 0; j < 4; j++)
                acc[i][j] = __builtin_amdgcn_mfma_f32_16x16x32_bf16(a[i], b[j], acc[i][j], 0, 0, 0);
        __syncthreads();
        cur ^= 1;
    }
#undef STAGE

    const int row0 = m0 + wm + (l >> 4) * 4;
    const int col0 = n0 + wn + lr;
    float bs[4];
#pragma unroll
    for (int j = 0; j < 4; j++) bs[j] = bias[col0 + j * 16];

    if (MODE == 0) {
        u16* qkv = (u16*)outv;
        const int plane = n0 >> 9;
        u16* pl = qkv + (size_t)plane * ((size_t)MP * CC);
#pragma unroll
        for (int i = 0; i < 4; i++) {
#pragma unroll
            for (int j = 0; j < 4; j++) {
                int gc = (col0 + j * 16) & 511;
#pragma unroll
                for (int r = 0; r < 4; r++) {
                    int gm = row0 + i * 16 + r;
                    pl[(size_t)gm * CC + gc] = f2bf(acc[i][j][r] + bs[j]);
                }
            }
        }
    } else {
        float* out = (float*)outv;
#pragma unroll
        for (int i = 0; i < 4; i++) {
#pragma unroll
            for (int j = 0; j < 4; j++) {
                int gn = col0 + j * 16;
#pragma unroll
                for (int r = 0; r < 4; r++) {
                    int gm = row0 + i * 16 + r;
                    if (gm < MM) out[(size_t)gm * NSZ + gn] = acc[i][j][r] + bs[j];
                }
            }
        }
    }
}

// ---------------------------------------------------------------------------
// ksv partials (NO max subtraction — k is O(1), exp(k) safe in f32):
// part[chunk][bh][kk][vv] = sum_{n in chunk} exp(k) * v
// psum[chunk][bh][kk]     = sum_{n in chunk} exp(k)
// ---------------------------------------------------------------------------
__global__ __launch_bounds__(256) void ksv_part_kernel(
    const u16* __restrict__ kbf, const u16* __restrict__ vbf,
    float* __restrict__ part, float* __restrict__ psum)
{
    int bh = blockIdx.x;
    int chunk = blockIdx.y;
    int b = bh >> 3, h = bh & 7;
    int n0 = chunk * 256;
    int n1 = (chunk == 3) ? NN : n0 + 256;

    __shared__ float ke[16][64];
    __shared__ float ve[16][64];

    int t = threadIdx.x;
    int lrow = t >> 4;
    int lcol = (t & 15) * 4;
    int tx = t & 15, ty = t >> 4;

    float acc[4][4] = {};
    float cs[4] = {};
    for (int nb = n0; nb < n1; nb += 16) {
        int n = nb + lrow;
        bool valid = n < n1;
        size_t off = ((size_t)(b * NN + n)) * CC + h * HD + lcol;  // padded plane
        u16x4 kr = *(const u16x4*)&kbf[off];
        u16x4 vr = *(const u16x4*)&vbf[off];
#pragma unroll
        for (int j = 0; j < 4; j++) {
            ke[lrow][lcol + j] = valid ? __expf(bf2f(kr[j])) : 0.f;
            ve[lrow][lcol + j] = valid ? bf2f(vr[j]) : 0.f;
        }
        __syncthreads();
#pragma unroll 4
        for (int d = 0; d < 16; d++) {
            f32x4 ka = *(const f32x4*)&ke[d][ty * 4];
            f32x4 vb = *(const f32x4*)&ve[d][tx * 4];
#pragma unroll
            for (int i = 0; i < 4; i++)
#pragma unroll
                for (int j = 0; j < 4; j++)
                    acc[i][j] = fmaf(ka[i], vb[j], acc[i][j]);
        }
        if (t < 16) {
#pragma unroll
            for (int d = 0; d < 16; d++) {
                f32x4 kv = *(const f32x4*)&ke[d][t * 4];
#pragma unroll
                for (int j = 0; j < 4; j++) cs[j] += kv[j];
            }
        }
        __syncthreads();
    }

    float* dst = part + ((size_t)chunk * 256 + bh) * 4096;
#pragma unroll
    for (int i = 0; i < 4; i++) {
        f32x4 o = {acc[i][0], acc[i][1], acc[i][2], acc[i][3]};
        *(f32x4*)&dst[(ty * 4 + i) * 64 + tx * 4] = o;
    }
    if (t < 16) {
        f32x4 o = {cs[0], cs[1], cs[2], cs[3]};
        *(f32x4*)&psum[((size_t)chunk * 256 + bh) * 64 + t * 4] = o;
    }
}

// ---------------------------------------------------------------------------
// ksvT[bh][vv][kk] = bf16( SCALE * (sum_c part[c][bh][kk][vv]) / sum_c psum )
// ---------------------------------------------------------------------------
__global__ __launch_bounds__(256) void ksv_reduceT_kernel(
    const float* __restrict__ part, const float* __restrict__ psum,
    u16* __restrict__ ksvT)
{
    int i = blockIdx.x * 256 + threadIdx.x;   // f32x4 units
    size_t e = (size_t)i * 4;
    int bh = (int)(e >> 12);
    int kk = ((int)e >> 6) & 63;
    int vv0 = (int)e & 63;
    f32x4 s = *(const f32x4*)&part[e];
    float cs = psum[bh * 64 + kk];
#pragma unroll
    for (int c = 1; c < 4; c++) {
        f32x4 p = *(const f32x4*)&part[(size_t)c * 256 * 4096 + e];
#pragma unroll
        for (int j = 0; j < 4; j++) s[j] += p[j];
        cs += psum[(size_t)c * 256 * 64 + bh * 64 + kk];
    }
    float inv = SCALE / cs;
#pragma unroll
    for (int j = 0; j < 4; j++)
        ksvT[(size_t)bh * 4096 + (vv0 + j) * 64 + kk] = f2bf(s[j] * inv);
}

// ---------------------------------------------------------------------------
// FUSED attn+ev: for 128 y-aligned pixel rows of one (b,h):
//   att = bf16( q @ ksvT^T ) + q ⊙ (dwconv(v) + cb)      [write-only]
// Block (yg, bh): rows n = 1+yg*128 .. +127 (pixels p = yg*128..+127).
// LDS: lq 16K (swizzled) + lk 8K (swizzled) + lv 40K (10-row zero-padded
// halo) + latt 16K (factor round-trip for conv-order re-layout) = 80 KB.
// ---------------------------------------------------------------------------
__global__ __launch_bounds__(256) void attn_ev_kernel(
    const u16* __restrict__ qbf, const u16* __restrict__ vbf,
    const u16* __restrict__ ksvT, const float* __restrict__ w7,
    const float* __restrict__ cbx, u16* __restrict__ attbf)
{
    int yg = blockIdx.x;            // 0..7
    int bh = blockIdx.y;
    int b = bh >> 3, h = bh & 7;
    const int nbase = 1 + yg * 128;

    __shared__ __align__(16) u16 lq[128 * 64];
    __shared__ __align__(16) u16 lk[64 * 64];
    __shared__ __align__(16) u16 lv[10 * 32 * 64];
    __shared__ __align__(16) u16 latt[128 * 64];

    int t = threadIdx.x;

    // ---- stage q (swizzled), ksvT (swizzled), v halo (linear, zero-padded)
#pragma unroll
    for (int i = 0; i < 4; i++) {
        int idx = t + i * 256;
        int row = idx >> 3, sl = idx & 7;
        u16x8 v = *(const u16x8*)&qbf[((size_t)(b * NN + nbase + row)) * CC + h * HD + sl * 8];
        *(u16x8*)&lq[row * 64 + ((sl ^ (row & 7)) * 8)] = v;
    }
#pragma unroll
    for (int i = 0; i < 2; i++) {
        int idx = t + i * 256;
        int col = idx >> 3, sl = idx & 7;
        u16x8 v = *(const u16x8*)&ksvT[(size_t)bh * 4096 + col * 64 + sl * 8];
        *(u16x8*)&lk[col * 64 + ((col & 7) ^ sl) * 8] = v;
    }
    {
        int x = t >> 3, sl = t & 7;
#pragma unroll
        for (int s = 0; s < 10; s++) {
            int yy = yg * 4 - 3 + s;
            u16x8 v;
            if (yy >= 0 && yy < 32)
                v = *(const u16x8*)&vbf[((size_t)(b * NN) + 1 + yy * 32 + x) * CC + h * HD + sl * 8];
            else {
#pragma unroll
                for (int j = 0; j < 8; j++) v[j] = 0;
            }
            *(u16x8*)&lv[s * 2048 + x * 64 + sl * 8] = v;
        }
    }
    __syncthreads();

    // ---- factor term via MFMA (4 waves x 32 rows)
    {
        int l = t & 63, w = t >> 6;
        int lr = l & 15, ls = l >> 4;
        f32x4 acc[2][4] = {};
#pragma unroll
        for (int kf = 0; kf < 2; kf++) {
            bf16x8 a[2], bf[4];
#pragma unroll
            for (int i = 0; i < 2; i++) {
                int row = w * 32 + i * 16 + lr;
                a[i] = *(const bf16x8*)&lq[row * 64 + (((kf * 4 + ls) ^ (row & 7)) * 8)];
            }
#pragma unroll
            for (int j = 0; j < 4; j++) {
                int col = j * 16 + lr;
                bf[j] = *(const bf16x8*)&lk[col * 64 + (((kf * 4 + ls) ^ (col & 7)) * 8)];
            }
#pragma unroll
            for (int i = 0; i < 2; i++)
#pragma unroll
                for (int j = 0; j < 4; j++)
                    acc[i][j] = __builtin_amdgcn_mfma_f32_16x16x32_bf16(a[i], bf[j], acc[i][j], 0, 0, 0);
        }
        // write factor to latt (bf16) for conv-order re-read
#pragma unroll
        for (int i = 0; i < 2; i++)
#pragma unroll
            for (int j = 0; j < 4; j++)
#pragma unroll
                for (int r = 0; r < 4; r++)
                    latt[(w * 32 + i * 16 + ls * 4 + r) * 64 + j * 16 + lr] =
                        f2bf(acc[i][j][r]);
    }
    __syncthreads();

    // ---- conv phase: thread = 8 px (x-run) x 4 ch
    int oct = t >> 4;               // 16 octets: yo = oct>>2, x0 = (oct&3)*8
    int cq = t & 15;
    int c4 = cq * 4;
    int c = h * HD + c4;            // global channel
    int yo = oct >> 2;
    int x0 = (oct & 3) * 8;

    float a2[8][4];
    {
        f32x4 b0 = *(const f32x4*)&cbx[c];
#pragma unroll
        for (int xi = 0; xi < 8; xi++)
#pragma unroll
            for (int j = 0; j < 4; j++) a2[xi][j] = b0[j];
    }

    for (int dy = 0; dy < 7; dy++) {
        int s = yo + dy;            // lv halo row (zero-padded -> no guard)
        float wr[7][4];
#pragma unroll
        for (int dx = 0; dx < 7; dx++)
            *(f32x4*)&wr[dx][0] = *(const f32x4*)&w7[(dy * 7 + dx) * 512 + c];
        u16x4 vv[14];
#pragma unroll
        for (int sxi = 0; sxi < 14; sxi++) {
            int sx = x0 - 3 + sxi;
            int sxc = sx < 0 ? 0 : (sx > 31 ? 31 : sx);
            vv[sxi] = *(const u16x4*)&lv[s * 2048 + sxc * 64 + c4];
        }
#pragma unroll
        for (int sxi = 0; sxi < 14; sxi++) {
            int sx = x0 - 3 + sxi;
            bool xval = (sx >= 0) && (sx < 32);
            float vf[4];
#pragma unroll
            for (int j = 0; j < 4; j++) vf[j] = xval ? bf2f(vv[sxi][j]) : 0.f;
            int lo = sxi - 6 > 0 ? sxi - 6 : 0;
            int hi = sxi < 7 ? sxi : 7;
#pragma unroll
            for (int xi = 0; xi < 8; xi++) {
                if (xi < lo || xi > hi) continue;
                int dx = sxi - xi;
#pragma unroll
                for (int j = 0; j < 4; j++)
                    a2[xi][j] = fmaf(vf[j], wr[dx][j], a2[xi][j]);
            }
        }
    }

    // ---- combine factor (latt) + q*ev and store
#pragma unroll
    for (int xi = 0; xi < 8; xi++) {
        int row = oct * 8 + xi;
        u16x4 at = *(const u16x4*)&latt[row * 64 + c4];
        // q from swizzled lq: slot = cq>>1, within-slot half = cq&1
        u16x4 qv = *(const u16x4*)&lq[row * 64 + (((cq >> 1) ^ (row & 7)) * 8) + (cq & 1) * 4];
        u16x4 ov;
#pragma unroll
        for (int j = 0; j < 4; j++)
            ov[j] = f2bf(bf2f(at[j]) + bf2f(qv[j]) * a2[xi][j]);
        *(u16x4*)&attbf[((size_t)(b * NN + nbase + row)) * CC + c] = ov;
    }
}

// ---------------------------------------------------------------------------
// n=0 row: attbf[b,0,c] = sum_kk q[b,0,h,kk] * ksvT[b,h,vv,kk]
// ---------------------------------------------------------------------------
__global__ __launch_bounds__(512) void att0_kernel(
    const u16* __restrict__ qbf, const u16* __restrict__ ksvT,
    u16* __restrict__ attbf)
{
    int b = blockIdx.x;
    int c = threadIdx.x;           // 0..511
    int h = c >> 6, vv = c & 63;
    const u16* q0 = qbf + (size_t)(b * NN) * CC + h * HD;
    const u16* kb = ksvT + ((size_t)(b * 8 + h)) * 4096 + vv * 64;
    float s = 0.f;
#pragma unroll 8
    for (int kk = 0; kk < 64; kk++)
        s = fmaf(bf2f(q0[kk]), bf2f(kb[kk]), s);
    attbf[(size_t)(b * NN) * CC + c] = f2bf(s);
}

// ---------------------------------------------------------------------------
extern "C" void kernel_launch(void* const* d_in, const int* in_sizes, int n_in,
                              void* d_out, int out_size, void* d_ws, size_t ws_size,
                              hipStream_t stream)
{
    const float* x     = (const float*)d_in[0];
    const float* Wqkv  = (const float*)d_in[1];
    const float* bqkv  = (const float*)d_in[2];
    const float* Wproj = (const float*)d_in[3];
    const float* bproj = (const float*)d_in[4];
    const float* ck3   = (const float*)d_in[5];
    const float* cb3   = (const float*)d_in[6];
    const float* ck5   = (const float*)d_in[7];
    const float* cb5   = (const float*)d_in[8];
    const float* ck7   = (const float*)d_in[9];
    const float* cb7   = (const float*)d_in[10];
    float* out = (float*)d_out;

    const size_t PLANE = (size_t)MP * CC;

    u16* xbf  = (u16*)d_ws;
    u16* qbf  = xbf + PLANE;
    u16* kbf  = qbf + PLANE;
    u16* vbf  = kbf + PLANE;
    u16* wqT  = vbf + PLANE;
    u16* wpT  = wqT + (size_t)1536 * 512;
    u16* ksvT = wpT + (size_t)512 * 512;           // 256*4096 bf16
    float* psum = (float*)(ksvT + (size_t)256 * 4096);  // 4*256*64
    float* part = psum + (size_t)4 * 256 * 64;     // 4*256*4096 f32
    float* w7   = part + (size_t)4 * 256 * 4096;   // 49*512
    float* cbx  = w7 + 49 * 512;                   // 512
    u16* attbf = xbf;                              // alias (x dead after qkv)

    // 1) converts + conv-weight expansion
    convert_x_kernel<<<(int)(PLANE / 8 / 256), 256, 0, stream>>>(x, xbf);
    convert_wt_kernel<<<1536 * 64 / 256, 256, 0, stream>>>(Wqkv, wqT, 1536);
    convert_wt_kernel<<<512 * 64 / 256, 256, 0, stream>>>(Wproj, wpT, 512);
    prep_w7_kernel<<<98, 256, 0, stream>>>(ck3, cb3, ck5, cb5, ck7, cb7, w7, cbx);

    // 2) qkv GEMM -> bf16 q/k/v planes
    {
        int nwg = 12 * (MP / 128);   // 3096
        gemm_bf16_kernel<0, 1536, 12><<<nwg, 256, 0, stream>>>(xbf, wqT, bqkv, qbf, nwg);
    }
    // 3) ksv partials (no-max, fused colsum) + transpose-reduce -> bf16 ksvT
    {
        dim3 grid(BB * HH, 4);
        ksv_part_kernel<<<grid, 256, 0, stream>>>(kbf, vbf, part, psum);
        ksv_reduceT_kernel<<<256 * 4096 / 4 / 256, 256, 0, stream>>>(part, psum, ksvT);
    }
    // 4) fused factor+conv -> attbf rows n>=1 ; n=0 via att0
    {
        dim3 grid(8, BB * HH);       // 2048 blocks
        attn_ev_kernel<<<grid, 256, 0, stream>>>(qbf, vbf, ksvT, w7, cbx, attbf);
        att0_kernel<<<BB, 512, 0, stream>>>(qbf, ksvT, attbf);
    }
    // 5) proj GEMM -> out
    {
        int nwg = 4 * (MP / 128);    // 1032
        gemm_bf16_kernel<1, 512, 4><<<nwg, 256, 0, stream>>>(attbf, wpT, bproj, out, nwg);
    }
}